// Round 15
// baseline (1721.717 us; speedup 1.0000x reference)
//
#include <hip/hip_runtime.h>

#define VV 50257
#define DD 50
#define TT 1024
#define BB 1024

typedef float v4f __attribute__((ext_vector_type(4)));

__device__ __forceinline__ float rl(float v, int lane) {
    return __int_as_float(__builtin_amdgcn_readlane(__float_as_int(v), lane));
}
__device__ __forceinline__ float sigmf(float x) { return 1.0f / (1.0f + __expf(-x)); }
__device__ __forceinline__ float tanhf_fast(float x) {
    float e = __expf(-2.0f * fabsf(x));
    return copysignf((1.0f - e) / (1.0f + e), x);
}

// P1[v][j] = b1[0][j] + sum_d emb[v][d] * kx1[d][j]   (one-time, ~0.5 GFLOP)
__global__ void proj_emb(const float* __restrict__ emb, const float* __restrict__ kx1,
                         const float* __restrict__ b1, float* __restrict__ P1) {
    int j = threadIdx.x;             // 0..95
    int v0 = blockIdx.x * 8;
    #pragma unroll 1
    for (int vv = 0; vv < 8; ++vv) {
        int v = v0 + vv;
        if (v >= VV) return;
        float acc = b1[j];
        #pragma unroll
        for (int d = 0; d < DD; ++d)
            acc += emb[v * DD + d] * kx1[d * 96 + j];
        P1[v * 96 + j] = acc;
    }
}

// r13 wave bodies (best: 1025 us, absmax 0.0; LDS uniform-broadcast matvecs)
// with ONE isolated change: the per-step __syncthreads is replaced by r11's
// verified decoupled producer/consumer flag protocol (8-deep x ring, prod/cons
// counters, fence-then-publish). Rationale: r13's per-SIMD issue is ~1100 cyc
// but wall is 2400 -- the block barrier aligns both waves' stall points (LDS
// broadcast latency + gate chains + rendezvous). r11's decoupling "failed" on
// the old readlane body (serial chain ~2900 cyc, nothing to reclaim); on r13's
// ~1300-cyc chains the lockstep overhead dominates -> rerun the experiment.
//  Wave B (wv=1, producer): at iter t: broadcast h1(t) from h1s (self-owned),
//    x(t)=h1(t)·kx2+b2[0] -> ring slot t&7 (flow ctrl: cons>=t-7), fence,
//    prod=t+1; GRU1 h1(t)->h1(t+1) (t<TT-1), publish h1s; prefetch p(t+2).
//  Wave A (wv=0, consumer): at iter t: m(t)=h2(t-1)·kh2+b2[1] from h2s
//    broadcast (self-owned); THEN poll prod>=t+1 (usually ready); read x(t);
//    gates -> h2(t); write h2s; cons=t+1.
__global__ __launch_bounds__(128, 1)
void rnn_main(const int* __restrict__ tokens, const float* __restrict__ P1,
              const float* __restrict__ kh1, const float* __restrict__ b1,
              const float* __restrict__ kx2, const float* __restrict__ kh2,
              const float* __restrict__ b2, const float* __restrict__ wg,
              const float* __restrict__ bg, const float* __restrict__ wd,
              const float* __restrict__ bd, float* __restrict__ out) {
    const int lane = threadIdx.x & 63;
    const int wv   = threadIdx.x >> 6;        // 0 = GRU2 consumer, 1 = GRU1 producer
    const int row  = blockIdx.x;
    const int l32  = lane & 31;
    const int* __restrict__ trow = tokens + row * TT;

    __shared__ float4 xb[8][64];              // x-triple ring, 8 deep
    __shared__ __align__(16) float h2s[64];   // h2 broadcast buffer (wave A only)
    __shared__ __align__(16) float h1s[32];   // h1 broadcast buffer (wave B only)
    __shared__ int prod;                      // x's published by B
    __shared__ int cons;                      // x's consumed by A

    if (threadIdx.x == 0) { prod = 0; cons = 0; }

    float w[192];
    float f0, f1, f2, f3 = 0.f, f4 = 0.f;     // role-dependent biases

    if (wv == 0) {
        h2s[lane] = 0.f;                      // h2(-1) = 0
        // kh2 columns: z=lane, r=64+lane, h=128+lane, interleaved by k
        #pragma unroll
        for (int k = 0; k < 64; ++k) {
            w[3 * k]     = kh2[k * 192 + lane];
            w[3 * k + 1] = kh2[k * 192 + 64 + lane];
            w[3 * k + 2] = kh2[k * 192 + 128 + lane];
        }
        f0 = b2[192 + lane];                  // recurrent biases b2[1]
        f1 = b2[256 + lane];
        f2 = b2[320 + lane];
    } else {
        if (lane < 32) h1s[lane] = 0.f;       // h1(-1) = 0
        // kh1: col lane (z for lane<32, r for lane>=32); h-col 64+lane for lane<32
        // kx2: 3 cols interleaved at w[64..191]
        #pragma unroll
        for (int k = 0; k < 32; ++k) {
            w[k]          = kh1[k * 96 + lane];
            w[32 + k]     = (lane < 32) ? kh1[k * 96 + 64 + lane] : 0.f;
            w[64 + 3 * k] = kx2[k * 192 + lane];
            w[65 + 3 * k] = kx2[k * 192 + 64 + lane];
            w[66 + 3 * k] = kx2[k * 192 + 128 + lane];
        }
        f0 = b1[96 + lane];                   // GRU1 recurrent z/r bias
        f1 = (lane < 32) ? b1[160 + lane] : 0.f;   // GRU1 recurrent h bias
        f2 = b2[lane];                        // input-proj biases b2[0]
        f3 = b2[64 + lane];
        f4 = b2[128 + lane];
    }

    __syncthreads();                          // the only barrier: init visibility

    if (wv == 1) {
        // ---------------- producer: GRU1 + x projection ----------------
        float h1 = 0.f;
        float pz, pr, ph;
        {
            const float* __restrict__ p = P1 + trow[0] * 96;
            pz = p[l32]; pr = p[32 + l32]; ph = p[64 + l32];   // p(0)
        }
        int tokc = trow[1];

        #pragma unroll 1
        for (int t = -1; t < TT; ++t) {
            // broadcast h1(t) (written at iter t-1; h1(-1)=0 from init)
            const v4f* __restrict__ h1v = reinterpret_cast<const v4f*>(h1s);
            v4f hb[8];
            #pragma unroll
            for (int kc = 0; kc < 8; ++kc) hb[kc] = h1v[kc];
            if (t >= 0) {
                // flow control: slot t&7 free once cons >= t-7
                if (t >= 8) {
                    int need = t - 7;
                    while (*(volatile int*)&cons < need) { __builtin_amdgcn_s_sleep(1); }
                }
                // x(t) = h1(t)·kx2 + b2[0]  -> ring slot t&7
                float xz = f2, xr = f3, xh = f4;
                #pragma unroll
                for (int kc = 0; kc < 8; ++kc) {
                    const int b = 64 + kc * 12;
                    xz += hb[kc].x * w[b];     xr += hb[kc].x * w[b + 1];  xh += hb[kc].x * w[b + 2];
                    xz += hb[kc].y * w[b + 3]; xr += hb[kc].y * w[b + 4];  xh += hb[kc].y * w[b + 5];
                    xz += hb[kc].z * w[b + 6]; xr += hb[kc].z * w[b + 7];  xh += hb[kc].z * w[b + 8];
                    xz += hb[kc].w * w[b + 9]; xr += hb[kc].w * w[b + 10]; xh += hb[kc].w * w[b + 11];
                }
                xb[t & 7][lane] = make_float4(xz, xr, xh, 0.f);
                __threadfence_block();        // drain data write before flag
                if (lane == 0) *(volatile int*)&prod = t + 1;
            }
            if (t < TT - 1) {
                // GRU1: h1(t) -> h1(t+1) using p(t+1)
                float az = f0, ah = f1;
                #pragma unroll
                for (int kc = 0; kc < 8; ++kc) {
                    az += hb[kc].x * w[4 * kc];     ah += hb[kc].x * w[32 + 4 * kc];
                    az += hb[kc].y * w[4 * kc + 1]; ah += hb[kc].y * w[32 + 4 * kc + 1];
                    az += hb[kc].z * w[4 * kc + 2]; ah += hb[kc].z * w[32 + 4 * kc + 2];
                    az += hb[kc].w * w[4 * kc + 3]; ah += hb[kc].w * w[32 + 4 * kc + 3];
                }
                float ra  = __shfl_xor(az, 32);   // r-preact to lanes 0..31
                float z1  = sigmf(pz + az);
                float g1  = sigmf(pr + ra);
                float hh1 = tanhf_fast(ph + g1 * ah);
                h1 = z1 * h1 + (1.f - z1) * hh1;  // h1(t+1) per-lane
                if (lane < 32) h1s[lane] = h1;    // publish broadcast copy (own wave)
                // prefetch p(t+2), token(t+3)
                const float* __restrict__ pn = P1 + tokc * 96;
                pz = pn[l32]; pr = pn[32 + l32]; ph = pn[64 + l32];
                tokc = trow[(t + 3 < TT) ? (t + 3) : (TT - 1)];
            }
        }
        return;                               // producer done
    }

    // ---------------- consumer: GRU2 + head ----------------
    float h2 = 0.f;
    #pragma unroll 1
    for (int t = 0; t < TT; ++t) {
        // m(t) = h2(t-1)·kh2 + b2[1], h2(t-1) broadcast from h2s (self-owned)
        const v4f* __restrict__ h2v = reinterpret_cast<const v4f*>(h2s);
        float mz = f0, mr = f1, mh = f2;
        #pragma unroll
        for (int kc = 0; kc < 16; ++kc) {
            v4f hb = h2v[kc];
            const int b = kc * 12;
            mz += hb.x * w[b];     mr += hb.x * w[b + 1];  mh += hb.x * w[b + 2];
            mz += hb.y * w[b + 3]; mr += hb.y * w[b + 4];  mh += hb.y * w[b + 5];
            mz += hb.z * w[b + 6]; mr += hb.z * w[b + 7];  mh += hb.z * w[b + 8];
            mz += hb.w * w[b + 9]; mr += hb.w * w[b + 10]; mh += hb.w * w[b + 11];
        }
        // x(t) should already be there (B runs ahead); poll then read
        while (*(volatile int*)&prod < t + 1) { __builtin_amdgcn_s_sleep(1); }
        __threadfence_block();
        float4 x  = xb[t & 7][lane];
        float z2  = sigmf(x.x + mz);
        float r2  = sigmf(x.y + mr);
        float hh2 = tanhf_fast(x.z + r2 * mh);   // reset after recurrent matmul
        h2 = z2 * h2 + (1.f - z2) * hh2;
        h2s[lane] = h2;                          // publish for next iteration (own wave)
        if (lane == 0) *(volatile int*)&cons = t + 1;   // x(t) consumed
    }

    // ---- tail: GLU + dense head ----
    float a0 = bg[lane], a1 = bg[64 + lane], a2 = bg[128 + lane], a3 = bg[192 + lane];
    #pragma unroll
    for (int k = 0; k < 64; ++k) {
        float s = rl(h2, k);
        a0 += s * wg[k * 256 + lane];
        a1 += s * wg[k * 256 + 64 + lane];
        a2 += s * wg[k * 256 + 128 + lane];
        a3 += s * wg[k * 256 + 192 + lane];
    }
    float g = a0 * sigmf(a2) * wd[lane] + a1 * sigmf(a3) * wd[64 + lane];
    g += __shfl_xor(g, 32); g += __shfl_xor(g, 16); g += __shfl_xor(g, 8);
    g += __shfl_xor(g, 4);  g += __shfl_xor(g, 2);  g += __shfl_xor(g, 1);
    if (lane == 0) out[row] = sigmf(g + bd[0]);
}

extern "C" void kernel_launch(void* const* d_in, const int* in_sizes, int n_in,
                              void* d_out, int out_size, void* d_ws, size_t ws_size,
                              hipStream_t stream) {
    const int*   tokens = (const int*)d_in[0];
    const float* emb = (const float*)d_in[1];
    const float* kx1 = (const float*)d_in[2];
    const float* kh1 = (const float*)d_in[3];
    const float* b1  = (const float*)d_in[4];
    const float* kx2 = (const float*)d_in[5];
    const float* kh2 = (const float*)d_in[6];
    const float* b2  = (const float*)d_in[7];
    const float* wg  = (const float*)d_in[8];
    const float* bg  = (const float*)d_in[9];
    const float* wd  = (const float*)d_in[10];
    const float* bd  = (const float*)d_in[11];
    float* out = (float*)d_out;
    float* P1  = (float*)d_ws;   // needs 50257*96*4 = 19.3 MB of workspace

    proj_emb<<<(VV + 7) / 8, 96, 0, stream>>>(emb, kx1, b1, P1);
    rnn_main<<<BB, 128, 0, stream>>>(tokens, P1, kh1, b1, kx2, kh2, b2,
                                     wg, bg, wd, bd, out);
}